// Round 1
// 552.152 us; speedup vs baseline: 1.0361x; 1.0361x over previous
//
#include <hip/hip_runtime.h>
#include <stddef.h>

// Problem constants (fixed by reference setup)
#define SROWS   16384
#define ODIM    6144
#define RMAX    64
#define SEGLEN  512
#define TM      64
#define TN      128

typedef float f4_t __attribute__((ext_vector_type(4)));

// out[i,n] = scale * sum_{k<keff} x[i, q*keff+k] * W[w, n, k], q = part(n)
// rows with l >= seg_len -> 0
// Single-barrier structure: stage full W tile (contiguous slab, coalesced
// float4) + full x slice once, then barrier-free k-loop.
// R1 changes vs baseline:
//  - block-uniform early-exit for fully-dead row blocks (l0 >= slen) and
//    keff==0 loras: store zeros, skip staging+barrier+k-loop (~25% of all
//    blocks are fully dead on average: mean seg_len 384 of 512)
//  - non-temporal output stores: 403 MB streaming write no longer
//    write-allocates in L2, keeping W/x staging tiles L2-resident
__global__ __launch_bounds__(256, 3) void lora_qkv_b_kernel(
    const float* __restrict__ x,              // (16384, 192)
    const float* __restrict__ w_all,          // (8, 6144, 64)
    const int*   __restrict__ weight_indices, // (32,)
    const int*   __restrict__ lora_ranks,     // (8,)
    const float* __restrict__ scalings,       // (8,)
    const int*   __restrict__ seg_lens,       // (32,)
    float*       __restrict__ out)            // (16384, 6144)
{
    __shared__ float xs[TM][RMAX];       // 16 KB, zero-padded past keff / invalid rows
    __shared__ float wlds[RMAX][TN + 4]; // 33 KB, k-major; +4 pad keeps 16B align + breaks bank stride

    const int rb = blockIdx.x;           // 0..255 (row block)
    const int cb = blockIdx.y;           // 0..47  (col block)
    const int i0 = rb * TM;
    const int n0 = cb * TN;

    const int seg  = i0 >> 9;            // 64 | 512: row block within one segment
    const int l0   = i0 & (SEGLEN - 1);
    const int w    = weight_indices[seg];
    int keff       = lora_ranks[w];
    if (keff > RMAX) keff = RMAX;
    const float scale = scalings[w];
    const int slen    = seg_lens[seg];

    const int tid    = threadIdx.x;
    const int rbase  = (tid >> 5) * 8;   // 8 groups x 8 rows = 64 rows
    const int nlocal = (tid & 31) * 4;   // 32 lanes x 4 cols = 128 cols

    // ---- fully-dead block: all 64 rows invalid, or rank-0 lora ----
    // Block-uniform predicate (same for all 256 threads), and no barrier has
    // been crossed yet, so early return is safe. Output was exactly 0.0 on
    // this path before (zeroed xs -> 0.0 accumulator -> 0.0*scale).
    if (keff == 0 || l0 >= slen) {
        const f4_t z = (f4_t)0.f;
        #pragma unroll
        for (int r = 0; r < 8; ++r) {
            const size_t row = (size_t)(i0 + rbase + r);
            __builtin_nontemporal_store(z, (f4_t*)(out + row * ODIM + n0 + nlocal));
        }
        return;
    }

    // part q: TN=128 divides 1024, so a col tile never straddles 4096/5120
    const int q    = (n0 < 4096) ? 0 : ((n0 < 5120) ? 1 : 2);
    const int qoff = q * keff;
    const float* Wb = w_all + ((size_t)w * ODIM + n0) * RMAX; // contiguous TN*64 slab

    // ---- stage W tile: wlds[k][n] = (k<keff) ? W[n0+n][k] : 0 ----
    // Perfectly coalesced: consecutive threads load consecutive float4s.
    for (int idx = tid * 4; idx < TN * RMAX; idx += 256 * 4) {
        const int n  = idx >> 6;
        const int k0 = idx & 63;
        float4 v = make_float4(0.f, 0.f, 0.f, 0.f);
        if (k0 < keff) {
            v = *(const float4*)(Wb + (size_t)n * RMAX + k0);
            if (k0 + 1 >= keff) v.y = 0.f;
            if (k0 + 2 >= keff) v.z = 0.f;
            if (k0 + 3 >= keff) v.w = 0.f;
        }
        wlds[k0 + 0][n] = v.x;
        wlds[k0 + 1][n] = v.y;
        wlds[k0 + 2][n] = v.z;
        wlds[k0 + 3][n] = v.w;
    }

    // ---- stage x slice: xs[r][k] = valid ? x[i0+r][qoff+k] : 0 ----
    // (scalar loads: qoff not 16B-aligned in general; row-contiguous -> coalesced)
    for (int idx = tid; idx < TM * RMAX; idx += 256) {
        const int r = idx >> 6;
        const int k = idx & 63;
        float v = 0.f;
        if (k < keff && (l0 + r) < slen) {
            v = x[(size_t)(i0 + r) * 192 + qoff + k];
        }
        xs[r][k] = v;
    }

    float acc[8][4];
    #pragma unroll
    for (int r = 0; r < 8; ++r)
        #pragma unroll
        for (int c = 0; c < 4; ++c) acc[r][c] = 0.f;

    __syncthreads();   // the only barrier

    const int keff4 = (keff + 3) & ~3;
    for (int k = 0; k < keff4; k += 4) {
        const float4 w0 = *(const float4*)(&wlds[k + 0][nlocal]);
        const float4 w1 = *(const float4*)(&wlds[k + 1][nlocal]);
        const float4 w2 = *(const float4*)(&wlds[k + 2][nlocal]);
        const float4 w3 = *(const float4*)(&wlds[k + 3][nlocal]);
        #pragma unroll
        for (int r = 0; r < 8; ++r) {
            const float4 xv = *(const float4*)(&xs[rbase + r][k]);
            acc[r][0] += xv.x * w0.x; acc[r][1] += xv.x * w0.y;
            acc[r][2] += xv.x * w0.z; acc[r][3] += xv.x * w0.w;
            acc[r][0] += xv.y * w1.x; acc[r][1] += xv.y * w1.y;
            acc[r][2] += xv.y * w1.z; acc[r][3] += xv.y * w1.w;
            acc[r][0] += xv.z * w2.x; acc[r][1] += xv.z * w2.y;
            acc[r][2] += xv.z * w2.z; acc[r][3] += xv.z * w2.w;
            acc[r][0] += xv.w * w3.x; acc[r][1] += xv.w * w3.y;
            acc[r][2] += xv.w * w3.z; acc[r][3] += xv.w * w3.w;
        }
    }

    // ---- epilogue: scale + non-temporal float4 stores ----
    // (invalid rows / padded k -> exact zeros, matching reference)
    #pragma unroll
    for (int r = 0; r < 8; ++r) {
        const size_t row = (size_t)(i0 + rbase + r);
        f4_t o;
        o.x = acc[r][0] * scale;
        o.y = acc[r][1] * scale;
        o.z = acc[r][2] * scale;
        o.w = acc[r][3] * scale;
        __builtin_nontemporal_store(o, (f4_t*)(out + row * ODIM + n0 + nlocal));
    }
}

extern "C" void kernel_launch(void* const* d_in, const int* in_sizes, int n_in,
                              void* d_out, int out_size, void* d_ws, size_t ws_size,
                              hipStream_t stream) {
    // setup_inputs order:
    // 0: x, 1: qkv_lora_b, 2: use_cuda_graph, 3: bs, 4: num_segments,
    // 5: seg_indptr, 6: weight_indices, 7: lora_ranks, 8: scalings,
    // 9: max_len, 10: seg_lens, 11: permutation, 12: output_offset,
    // 13: max_qkv_out_dim
    const float* x    = (const float*)d_in[0];
    const float* wb   = (const float*)d_in[1];
    const int*   widx = (const int*)d_in[6];
    const int*   rks  = (const int*)d_in[7];
    const float* scl  = (const float*)d_in[8];
    const int*   sln  = (const int*)d_in[10];
    float* out = (float*)d_out;

    dim3 grid(SROWS / TM, ODIM / TN);
    lora_qkv_b_kernel<<<grid, 256, 0, stream>>>(x, wb, widx, rks, scl, sln, out);
}

// Round 2
// 483.733 us; speedup vs baseline: 1.1826x; 1.1414x over previous
//
#include <hip/hip_runtime.h>
#include <stddef.h>

// Problem constants (fixed by reference setup)
#define SROWS   16384
#define ODIM    6144
#define RMAX    64
#define SEGLEN  512
#define TM      64
#define TN      128
#define XDIM    192

typedef float f4_t __attribute__((ext_vector_type(4)));

// out[i,n] = scale * sum_{k<keff} x[i, q*keff+k] * W[w, n, k], q = part(n)
// rows with l >= seg_len -> 0
//
// R2 restructure: block = (segment, col-tile, row-half). Each block stages its
// 32 KB W tile ONCE and loops 4 row-chunks of 64 through a single 16 KB xs
// buffer (2 barriers/chunk), prefetching chunk c+1's x into registers before
// chunk c's k-loop (latency hides under FMAs; barrier's vmcnt(0) lands after).
// W read traffic: 403 MB -> 100 MB. slen >= 256 always => half 0 never needs
// row masking. Same FMA order as R1 => bitwise-identical output.
__global__ __launch_bounds__(256, 3) void lora_qkv_b_kernel(
    const float* __restrict__ x,              // (16384, 192)
    const float* __restrict__ w_all,          // (8, 6144, 64)
    const int*   __restrict__ weight_indices, // (32,)
    const int*   __restrict__ lora_ranks,     // (8,)
    const float* __restrict__ scalings,       // (8,)
    const int*   __restrict__ seg_lens,       // (32,)
    float*       __restrict__ out)            // (16384, 6144)
{
    __shared__ float xs[TM][RMAX];       // 16 KB
    __shared__ float wlds[RMAX][TN + 4]; // 33 KB, k-major; +4 pad

    const int seg   = blockIdx.x;        // 0..31
    const int cb    = blockIdx.y;        // 0..47
    const int half  = blockIdx.z;        // 0..1
    const int n0    = cb * TN;
    const int segbase = seg * SEGLEN;
    const int lbase = half * (SEGLEN / 2);   // 0 or 256

    const int w    = weight_indices[seg];
    int keff       = lora_ranks[w];
    if (keff > RMAX) keff = RMAX;
    const float scale = scalings[w];
    const int slen    = seg_lens[seg];

    const int tid    = threadIdx.x;
    const int rbase  = (tid >> 5) * 8;   // 8 groups x 8 rows
    const int nlocal = (tid & 31) * 4;   // 32 lanes x 4 cols

    // ---- fully-dead half (rank-0 lora, or slen==256 && half==1): zeros ----
    if (keff == 0 || lbase >= slen) {
        const f4_t z = (f4_t)0.f;
        for (int c = 0; c < 4; ++c) {
            const int i0 = segbase + lbase + c * TM;
            #pragma unroll
            for (int r = 0; r < 8; ++r)
                __builtin_nontemporal_store(
                    z, (f4_t*)(out + (size_t)(i0 + rbase + r) * ODIM + n0 + nlocal));
        }
        return;
    }

    // part q: TN=128 divides 1024, so a col tile never straddles 4096/5120
    const int q    = (n0 < 4096) ? 0 : ((n0 < 5120) ? 1 : 2);
    const int qoff = q * keff;
    const float* Wb = w_all + ((size_t)w * ODIM + n0) * RMAX; // contiguous TN*64 slab

    // ---- stage W tile ONCE: wlds[k][n] = (k<keff) ? W[n0+n][k] : 0 ----
    for (int idx = tid * 4; idx < TN * RMAX; idx += 256 * 4) {
        const int n  = idx >> 6;
        const int k0 = idx & 63;
        float4 v = make_float4(0.f, 0.f, 0.f, 0.f);
        if (k0 < keff) {
            v = *(const float4*)(Wb + (size_t)n * RMAX + k0);
            if (k0 + 1 >= keff) v.y = 0.f;
            if (k0 + 2 >= keff) v.z = 0.f;
            if (k0 + 3 >= keff) v.w = 0.f;
        }
        wlds[k0 + 0][n] = v.x;
        wlds[k0 + 1][n] = v.y;
        wlds[k0 + 2][n] = v.z;
        wlds[k0 + 3][n] = v.w;
    }

    // x element ownership: thread loads column kk, rows r0 + 4m (m=0..15)
    const int kk = tid & 63;
    const int r0 = tid >> 6;             // 0..3
    const int keff4 = (keff + 3) & ~3;

    // ---- prefetch chunk 0 into registers ----
    // (always in-bounds: segment spans 512 real x rows; qoff+kk <= 191)
    float pref[16];
    {
        const float* p = x + ((size_t)(segbase + lbase) + r0) * XDIM + qoff + kk;
        #pragma unroll
        for (int m = 0; m < 16; ++m) pref[m] = p[(size_t)m * 4 * XDIM];
    }

    for (int c = 0; c < 4; ++c) {
        const int l0 = lbase + c * TM;
        const int i0 = segbase + l0;

        if (l0 >= slen) {   // dead chunk (uniform): zeros, no barrier touched
            const f4_t z = (f4_t)0.f;
            #pragma unroll
            for (int r = 0; r < 8; ++r)
                __builtin_nontemporal_store(
                    z, (f4_t*)(out + (size_t)(i0 + rbase + r) * ODIM + n0 + nlocal));
            continue;
        }

        // ---- commit prefetched x -> xs (row mask only; k>=keff is killed by
        // the zeroed wlds rows, so no k mask needed) ----
        if (l0 + TM <= slen) {
            #pragma unroll
            for (int m = 0; m < 16; ++m) xs[m * 4 + r0][kk] = pref[m];
        } else {
            #pragma unroll
            for (int m = 0; m < 16; ++m)
                xs[m * 4 + r0][kk] = (l0 + m * 4 + r0 < slen) ? pref[m] : 0.f;
        }

        __syncthreads();   // xs (and, first time, wlds) ready

        // ---- issue next chunk's prefetch; lands during the k-loop ----
        if (c < 3 && l0 + TM < slen) {
            const float* p = x + ((size_t)(i0 + TM) + r0) * XDIM + qoff + kk;
            #pragma unroll
            for (int m = 0; m < 16; ++m) pref[m] = p[(size_t)m * 4 * XDIM];
        }

        float acc[8][4];
        #pragma unroll
        for (int r = 0; r < 8; ++r)
            #pragma unroll
            for (int cc = 0; cc < 4; ++cc) acc[r][cc] = 0.f;

        for (int k = 0; k < keff4; k += 4) {
            const float4 w0 = *(const float4*)(&wlds[k + 0][nlocal]);
            const float4 w1 = *(const float4*)(&wlds[k + 1][nlocal]);
            const float4 w2 = *(const float4*)(&wlds[k + 2][nlocal]);
            const float4 w3 = *(const float4*)(&wlds[k + 3][nlocal]);
            #pragma unroll
            for (int r = 0; r < 8; ++r) {
                const float4 xv = *(const float4*)(&xs[rbase + r][k]);
                acc[r][0] += xv.x * w0.x; acc[r][1] += xv.x * w0.y;
                acc[r][2] += xv.x * w0.z; acc[r][3] += xv.x * w0.w;
                acc[r][0] += xv.y * w1.x; acc[r][1] += xv.y * w1.y;
                acc[r][2] += xv.y * w1.z; acc[r][3] += xv.y * w1.w;
                acc[r][0] += xv.z * w2.x; acc[r][1] += xv.z * w2.y;
                acc[r][2] += xv.z * w2.z; acc[r][3] += xv.z * w2.w;
                acc[r][0] += xv.w * w3.x; acc[r][1] += xv.w * w3.y;
                acc[r][2] += xv.w * w3.z; acc[r][3] += xv.w * w3.w;
            }
        }

        __syncthreads();   // all waves done reading xs before next overwrite

        // ---- epilogue: overlaps next iteration's xs commit ----
        #pragma unroll
        for (int r = 0; r < 8; ++r) {
            const size_t row = (size_t)(i0 + rbase + r);
            f4_t o;
            o.x = acc[r][0] * scale;
            o.y = acc[r][1] * scale;
            o.z = acc[r][2] * scale;
            o.w = acc[r][3] * scale;
            __builtin_nontemporal_store(o, (f4_t*)(out + row * ODIM + n0 + nlocal));
        }
    }
}

extern "C" void kernel_launch(void* const* d_in, const int* in_sizes, int n_in,
                              void* d_out, int out_size, void* d_ws, size_t ws_size,
                              hipStream_t stream) {
    // setup_inputs order:
    // 0: x, 1: qkv_lora_b, 2: use_cuda_graph, 3: bs, 4: num_segments,
    // 5: seg_indptr, 6: weight_indices, 7: lora_ranks, 8: scalings,
    // 9: max_len, 10: seg_lens, 11: permutation, 12: output_offset,
    // 13: max_qkv_out_dim
    const float* x    = (const float*)d_in[0];
    const float* wb   = (const float*)d_in[1];
    const int*   widx = (const int*)d_in[6];
    const int*   rks  = (const int*)d_in[7];
    const float* scl  = (const float*)d_in[8];
    const int*   sln  = (const int*)d_in[10];
    float* out = (float*)d_out;

    dim3 grid(32, ODIM / TN, 2);   // (segment, col tile, row half)
    lora_qkv_b_kernel<<<grid, 256, 0, stream>>>(x, wb, widx, rks, scl, sln, out);
}